// Round 10
// baseline (339.819 us; speedup 1.0000x reference)
//
#include <hip/hip_runtime.h>
#include <hip/hip_bf16.h>

#define BB 8
#define CC 128
#define HH 128
#define WW 128
#define HW (HH*WW)
#define EE 4
#define EPSL 1e-6f
#define PT1 8
#define LNP 128

typedef __attribute__((ext_vector_type(8))) short bf16x8;
typedef __attribute__((ext_vector_type(4))) float f32x4;

__device__ inline float b2f(unsigned short u){
  union { unsigned int i; float f; } v; v.i = ((unsigned int)u)<<16; return v.f;
}
__device__ inline unsigned short f2b(float f){
  union { float f; unsigned int i; } v; v.f = f;
  unsigned int x = v.i;
  return (unsigned short)((x + 0x7fffu + ((x>>16)&1u)) >> 16);
}
// LDS swizzle for [px][c] bf16 tiles (256B rows)
__device__ inline int swz(int px, int cbyte){
  return cbyte ^ ((((px)&7) ^ (((px)>>3)&3)) << 4);
}

// ---- K1: LayerNorm over C per pixel + feat partial sums (from LDS tile) -------
__global__ __launch_bounds__(128) void k_ln(
    const float* __restrict__ x, const float* __restrict__ gamma,
    const float* __restrict__ beta, unsigned short* __restrict__ xin,
    float* __restrict__ feat_sum) {
  int b = blockIdx.y;
  int p0 = blockIdx.x*LNP;
  int tid = threadIdx.x;
  const float* xb = x + (size_t)b*CC*HW + p0 + tid;
  float s=0.f, s2=0.f;
  for (int c=0;c<CC;c++){ float v = xb[(size_t)c*HW]; s+=v; s2+=v*v; }
  float mu = s*(1.f/CC);
  float var = s2*(1.f/CC) - mu*mu;
  float rs = rsqrtf(var + EPSL);

  __shared__ unsigned short tile[LNP][CC+8];
  __shared__ float lfeat[CC];
  if (tid < CC) lfeat[tid]=0.f;
  for (int c0=0;c0<CC;c0+=8){
    union { bf16x8 v; unsigned short s[8]; } pk;
    #pragma unroll
    for (int j=0;j<8;j++){
      float v = (xb[(size_t)(c0+j)*HW]-mu)*rs*gamma[c0+j]+beta[c0+j];
      pk.s[j]=f2b(v);
    }
    *(bf16x8*)&tile[tid][c0] = pk.v;
  }
  __syncthreads();
  // coalesced global writeout
  unsigned short* xo = xin + ((size_t)b*HW + p0)*CC;
  #pragma unroll
  for (int it=0; it<16; ++it){
    int i = it*LNP + tid;
    int pr = i>>4, ck = (i&15)*8;
    *(bf16x8*)(xo + (size_t)i*8) = *(bf16x8*)&tile[pr][ck];
  }
  // feat partial: thread = (cg, po) covers 16 px x 8 ch from LDS tile
  int cg = (tid & 15) * 8;
  int po = tid >> 4;              // 0..7
  float fa[8] = {};
  #pragma unroll
  for (int i=0;i<16;i++){
    int px = i*8 + po;
    bf16x8 v = *(bf16x8*)&tile[px][cg];
    #pragma unroll
    for (int j=0;j<8;j++) fa[j] += b2f((unsigned short)v[j]);
  }
  #pragma unroll
  for (int j=0;j<8;j++) atomicAdd(&lfeat[cg+j], fa[j]);
  __syncthreads();
  if (tid < CC) atomicAdd(&feat_sum[b*CC+tid], lfeat[tid]);
}

// ---- K2: router (1 block) ------------------------------------------------------
__global__ __launch_bounds__(256) void k_router(
    const float* __restrict__ feat_sum, const float* __restrict__ prompt,
    const float* __restrict__ rw, const float* __restrict__ rb,
    const float* __restrict__ b2, const float* __restrict__ pw,
    const float* __restrict__ pb,
    int* __restrict__ eidx, float* __restrict__ wgt, float* __restrict__ bias_out) {
  __shared__ float logits[BB][EE];
  __shared__ float gate[BB][EE];
  __shared__ float cb[BB][CC];
  int t = threadIdx.x;
  if (t < BB*EE) {
    int b = t/EE, e = t%EE;
    float acc = rb[e];
    for (int c=0;c<CC;c++) acc += (feat_sum[b*CC+c]*(1.f/HW))*rw[c*EE+e];
    for (int c=0;c<CC;c++) acc += prompt[b*CC+c]*rw[(CC+c)*EE+e];
    logits[b][e]=acc;
  }
  __syncthreads();
  if (t < BB) {
    int b=t;
    float m=-1e30f;
    for(int e=0;e<EE;e++) m=fmaxf(m,logits[b][e]);
    float s=0.f, pr[EE];
    for(int e=0;e<EE;e++){ pr[e]=__expf(logits[b][e]-m); s+=pr[e]; }
    for(int e=0;e<EE;e++){ pr[e]/=s; gate[b][e]=0.f; }
    int i1=0; for(int e=1;e<EE;e++) if (pr[e]>pr[i1]) i1=e;
    int i2=-1; for(int e=0;e<EE;e++){ if(e==i1) continue; if(i2<0||pr[e]>pr[i2]) i2=e; }
    eidx[b*2]=i1; eidx[b*2+1]=i2;
    wgt[b*2]=pr[i1]; wgt[b*2+1]=pr[i2];
    gate[b][i1]=pr[i1]; gate[b][i2]=pr[i2];
  }
  __syncthreads();
  for (int i=t;i<BB*CC;i+=256){
    int b=i/CC, c=i%CC;
    float a=0.f;
    for(int e=0;e<EE;e++) a += gate[b][e]*b2[e*CC+c];
    cb[b][c]=a;
  }
  __syncthreads();
  for (int i=t;i<BB*CC;i+=256){
    int b=i/CC, o=i%CC;
    float a=pb[o];
    for (int c=0;c<CC;c++) a += pw[o*CC+c]*cb[b][c];
    bias_out[b*CC+o]=a;
  }
}

// ---- K3: prep: w2p[e] = bf16(pw @ w2[e]); w1b[e] = bf16(w1[e]) -----------------
__global__ __launch_bounds__(128) void k_prep(
    const float* __restrict__ pw, const float* __restrict__ w2,
    const float* __restrict__ w1,
    unsigned short* __restrict__ w2p, unsigned short* __restrict__ w1b){
  int eo = blockIdx.x; int e = eo/CC, o = eo%CC;
  int c = threadIdx.x;
  float a=0.f;
  for (int m=0;m<CC;m++) a += pw[o*CC+m]*w2[((size_t)e*CC+m)*CC+c];
  w2p[((size_t)e*CC+o)*CC+c] = f2b(a);
  w1b[((size_t)e*CC+o)*CC+c] = f2b(w1[((size_t)e*CC+o)*CC+c]);
}

// ---- K3b: w2s[bk] = bf16(wgt[bk] * w2p[e[bk]]) ---------------------------------
__global__ __launch_bounds__(256) void k_scalew2(
    const unsigned short* __restrict__ w2p, const int* __restrict__ eidx,
    const float* __restrict__ wgt, unsigned short* __restrict__ w2s){
  int bk = blockIdx.y;
  int e = eidx[bk]; float wv = wgt[bk];
  int i = blockIdx.x*256 + threadIdx.x;
  const unsigned short* src = w2p + (size_t)e*CC*CC;
  w2s[(size_t)bk*CC*CC + i] = f2b(wv * b2f(src[i]));
}

// ---- K4: GEMM1 (MFMA bf16): t1[bk][p][o] = w1b[e] @ xin[b] + b1[e] -------------
__global__ __launch_bounds__(256) void k_gemm1(
    const unsigned short* __restrict__ xin, const unsigned short* __restrict__ w1b,
    const float* __restrict__ b1, const int* __restrict__ eidx,
    unsigned short* __restrict__ t1) {
  int bk = blockIdx.y; int b = bk>>1; int e = eidx[bk];
  int wave = threadIdx.x>>6, lane = threadIdx.x&63;
  int lr = lane&15, lg = lane>>4;
  int ob = wave*32;
  const unsigned short* Ae = w1b + (size_t)e*CC*CC;
  bf16x8 A[2][4];
  #pragma unroll
  for (int of=0; of<2; of++)
    #pragma unroll
    for (int k0=0; k0<4; k0++)
      A[of][k0] = *(const bf16x8*)(Ae + (size_t)(ob+of*16+lr)*CC + k0*32 + lg*8);
  float bs[2][4];
  #pragma unroll
  for (int of=0; of<2; of++)
    #pragma unroll
    for (int r=0; r<4; r++)
      bs[of][r] = b1[e*CC + ob + of*16 + lg*4 + r];

  int p_start = blockIdx.x * (32*PT1);
  const unsigned short* Xb = xin + ((size_t)b*HW + p_start)*CC;
  unsigned short* T = t1 + ((size_t)bk*HW + p_start)*CC;

  bf16x8 Ba[2][4], Bb[2][4];
  auto loadB = [&](bf16x8 (&Bf)[2][4], int tt){
    const unsigned short* Xt = Xb + (size_t)tt*32*CC;
    #pragma unroll
    for (int pf=0; pf<2; pf++)
      #pragma unroll
      for (int k0=0; k0<4; k0++)
        Bf[pf][k0] = *(const bf16x8*)(Xt + (size_t)(pf*16+lr)*CC + k0*32 + lg*8);
  };
  auto comp = [&](bf16x8 (&Bf)[2][4], int tt){
    f32x4 acc[2][2];
    #pragma unroll
    for (int of=0; of<2; of++){ acc[of][0]=(f32x4){0,0,0,0}; acc[of][1]=(f32x4){0,0,0,0}; }
    #pragma unroll
    for (int k0=0; k0<4; k0++)
      #pragma unroll
      for (int of=0; of<2; of++)
        #pragma unroll
        for (int pf=0; pf<2; pf++)
          acc[of][pf] = __builtin_amdgcn_mfma_f32_16x16x32_bf16(A[of][k0], Bf[pf][k0], acc[of][pf],0,0,0);
    unsigned short* Tt = T + (size_t)tt*32*CC;
    #pragma unroll
    for (int of=0; of<2; of++){
      int o0 = ob + of*16 + lg*4;
      #pragma unroll
      for (int pf=0; pf<2; pf++){
        union { unsigned long long u; unsigned short s[4]; } pk;
        #pragma unroll
        for (int r=0; r<4; r++) pk.s[r]=f2b(acc[of][pf][r]+bs[of][r]);
        *(unsigned long long*)(Tt + (size_t)(pf*16+lr)*CC + o0) = pk.u;
      }
    }
  };

  loadB(Ba, 0);
  #pragma unroll
  for (int t=0; t<PT1; t++){
    if ((t&1)==0){ if (t+1<PT1) loadB(Bb, t+1); comp(Ba, t); }
    else         { if (t+1<PT1) loadB(Ba, t+1); comp(Bb, t); }
  }
}

// ---- K5: FUSED dw3x3+GELU -> LDS -> GEMM2 + residual. Half-row time-share ------
// Block = (row h, batch b). For each 64-px half: dw both experts into 2x16KB
// swizzled tiles, then MFMA from LDS. LDS ~42KB -> 3 blocks/CU.
__global__ __launch_bounds__(256) void k_dwg2(
    const unsigned short* __restrict__ t1, const float* __restrict__ dw,
    const float* __restrict__ bdw, const int* __restrict__ eidx,
    const unsigned short* __restrict__ w2s, const float* __restrict__ bias_out,
    const float* __restrict__ x, float* __restrict__ out) {
  int b = blockIdx.y;
  int h = blockIdx.x;
  int tid = threadIdx.x;

  __shared__ unsigned short tile2[2][64*CC];   // 2 x 16KB
  __shared__ float skd2[2][CC*9];
  __shared__ float sbd2[2][CC];

  int e0 = eidx[b*2], e1 = eidx[b*2+1];
  for (int i=tid; i<2*CC*9; i+=256){
    int kk = i/(CC*9), j = i%(CC*9);
    skd2[kk][j] = dw[(size_t)(kk? e1:e0)*CC*9 + j];
  }
  for (int i=tid; i<2*CC; i+=256){
    int kk = i/CC, j = i%CC;
    sbd2[kk][j] = bdw[(kk? e1:e0)*CC + j];
  }

  int wave = tid>>6, lane = tid&63;
  int lr = lane&15, lg = lane>>4;
  int ob = wave*32;
  bf16x8 A[2][2][4];
  #pragma unroll
  for (int kk=0; kk<2; kk++){
    const unsigned short* Ae = w2s + (size_t)(b*2+kk)*CC*CC;
    #pragma unroll
    for (int of=0; of<2; of++)
      #pragma unroll
      for (int k0=0; k0<4; k0++)
        A[kk][of][k0] = *(const bf16x8*)(Ae + (size_t)(ob+of*16+lr)*CC + k0*32 + lg*8);
  }
  float bo[2][4];
  #pragma unroll
  for (int of=0; of<2; of++)
    #pragma unroll
    for (int r=0; r<4; r++)
      bo[of][r] = bias_out[b*CC + ob + of*16 + lg*4 + r];

  __syncthreads();

  int cg = (tid & 15) * 8;      // channel group
  int slot = tid >> 4;          // 0..15, 4 px each
  const float* xb = x + (size_t)b*CC*HW + (size_t)h*WW;
  float* obp = out + (size_t)b*CC*HW + (size_t)h*WW;

  #pragma unroll
  for (int half=0; half<2; half++){
    int pbase = half*64;
    // ---- dw phase: both experts into tiles
    #pragma unroll
    for (int kk=0; kk<2; kk++){
      float acc[4][8];
      #pragma unroll
      for (int i=0;i<4;i++)
        #pragma unroll
        for (int j=0;j<8;j++) acc[i][j] = sbd2[kk][cg+j];
      const unsigned short* rowbase = t1 + ((size_t)(b*2+kk)*HW + (size_t)h*WW)*CC + cg;
      #pragma unroll
      for (int dy=0; dy<3; dy++){
        int h2 = h + dy - 1;
        if (h2 < 0 || h2 >= HH) continue;
        const unsigned short* rp = rowbase + (size_t)(dy-1)*WW*CC;
        bf16x8 v[6];
        #pragma unroll
        for (int t=0; t<6; t++){
          int wc = pbase + slot*4 + t - 1;
          if (wc >= 0 && wc < WW) v[t] = *(const bf16x8*)(rp + (size_t)wc*CC);
          else                    v[t] = (bf16x8){0,0,0,0,0,0,0,0};
        }
        #pragma unroll
        for (int dx=0; dx<3; dx++){
          float wk[8];
          #pragma unroll
          for (int j=0; j<8; j++) wk[j] = skd2[kk][(cg+j)*9 + dy*3 + dx];
          #pragma unroll
          for (int i=0; i<4; i++)
            #pragma unroll
            for (int j=0; j<8; j++)
              acc[i][j] += b2f((unsigned short)v[i+dx][j]) * wk[j];
        }
      }
      #pragma unroll
      for (int i=0; i<4; i++){
        union { bf16x8 v; unsigned short s[8]; } pk;
        #pragma unroll
        for (int j=0; j<8; j++){
          float a = acc[i][j];
          pk.s[j] = f2b(0.5f*a*(1.f+erff(a*0.70710678f)));
        }
        int p = slot*4 + i;
        *(bf16x8*)((char*)&tile2[kk][0] + p*256 + swz(p, cg*2)) = pk.v;
      }
    }
    __syncthreads();
    // ---- MFMA phase: 2 local 32-px tiles
    #pragma unroll
    for (int ttl=0; ttl<2; ttl++){
      f32x4 acc2[2][2];
      #pragma unroll
      for (int of=0; of<2; of++){ acc2[of][0]=(f32x4){0,0,0,0}; acc2[of][1]=(f32x4){0,0,0,0}; }
      #pragma unroll
      for (int kk=0; kk<2; kk++){
        #pragma unroll
        for (int k0=0; k0<4; k0++){
          int cb = k0*64 + lg*16;
          int r0 = ttl*32 + lr, r1 = ttl*32 + 16 + lr;
          bf16x8 B0 = *(bf16x8*)((char*)&tile2[kk][0] + r0*256 + swz(r0, cb));
          bf16x8 B1 = *(bf16x8*)((char*)&tile2[kk][0] + r1*256 + swz(r1, cb));
          #pragma unroll
          for (int of=0; of<2; of++){
            acc2[of][0] = __builtin_amdgcn_mfma_f32_16x16x32_bf16(A[kk][of][k0], B0, acc2[of][0],0,0,0);
            acc2[of][1] = __builtin_amdgcn_mfma_f32_16x16x32_bf16(A[kk][of][k0], B1, acc2[of][1],0,0,0);
          }
        }
      }
      #pragma unroll
      for (int of=0; of<2; of++){
        int o0 = ob + of*16 + lg*4;
        #pragma unroll
        for (int r=0; r<4; r++){
          #pragma unroll
          for (int pf=0; pf<2; pf++){
            size_t idx = (size_t)(o0+r)*HW + pbase + ttl*32 + pf*16 + lr;
            obp[idx] = xb[idx] + acc2[of][pf][r] + bo[of][r];
          }
        }
      }
    }
    __syncthreads();
  }
}

extern "C" void kernel_launch(void* const* d_in, const int* in_sizes, int n_in,
                              void* d_out, int out_size, void* d_ws, size_t ws_size,
                              hipStream_t stream) {
  const float* x      = (const float*)d_in[0];
  const float* prompt = (const float*)d_in[1];
  const float* gamma  = (const float*)d_in[2];
  const float* beta   = (const float*)d_in[3];
  const float* rw     = (const float*)d_in[4];
  const float* rb     = (const float*)d_in[5];
  const float* w1     = (const float*)d_in[6];
  const float* b1     = (const float*)d_in[7];
  const float* dw     = (const float*)d_in[8];
  const float* bdw    = (const float*)d_in[9];
  const float* w2     = (const float*)d_in[10];
  const float* b2     = (const float*)d_in[11];
  const float* pw     = (const float*)d_in[12];
  const float* pb     = (const float*)d_in[13];
  float* out = (float*)d_out;

  char* base = (char*)d_ws;
  size_t off = 0;
  auto alloc = [&](size_t bytes)->void* {
    void* p = base + off;
    off = (off + bytes + 255) & ~(size_t)255;
    return p;
  };
  unsigned short* xin  = (unsigned short*)alloc((size_t)BB*HW*CC*2);     // 32 MiB [b][p][c]
  unsigned short* t1   = (unsigned short*)alloc((size_t)BB*2*HW*CC*2);   // 64 MiB [bk][p][o]
  unsigned short* w1b  = (unsigned short*)alloc((size_t)EE*CC*CC*2);
  unsigned short* w2p  = (unsigned short*)alloc((size_t)EE*CC*CC*2);
  unsigned short* w2s  = (unsigned short*)alloc((size_t)BB*2*CC*CC*2);
  float* feat_sum      = (float*)alloc(BB*CC*4);
  int*   eidx          = (int*)alloc(BB*2*4);
  float* wgt           = (float*)alloc(BB*2*4);
  float* bias_out      = (float*)alloc(BB*CC*4);

  hipMemsetAsync(feat_sum, 0, BB*CC*4, stream);

  k_ln<<<dim3(HW/LNP, BB), LNP, 0, stream>>>(x, gamma, beta, xin, feat_sum);
  k_prep<<<dim3(EE*CC), 128, 0, stream>>>(pw, w2, w1, w2p, w1b);
  k_router<<<dim3(1), 256, 0, stream>>>(feat_sum, prompt, rw, rb, b2, pw, pb,
                                        eidx, wgt, bias_out);
  k_scalew2<<<dim3(CC*CC/256, BB*2), 256, 0, stream>>>(w2p, eidx, wgt, w2s);
  k_gemm1<<<dim3(HW/(32*PT1), BB*2), 256, 0, stream>>>(xin, w1b, b1, eidx, t1);
  k_dwg2<<<dim3(HH, BB), 256, 0, stream>>>(t1, dw, bdw, eidx, w2s, bias_out, x, out);
}